// Round 16
// baseline (37.559 us; speedup 1.0000x reference)
//
#include <hip/hip_runtime.h>
#include <math.h>

// SCTC-SB loss, round 16 = round 15 + algebraic DOUBLE-STEP in full chunks:
// two consecutive recursion steps composed into one 4/5-tap linear update
// whose coefficients depend only on the two steps' probs (computed in the
// shadow). Serial depth per timestep ~halves. Tails keep single-step code.
// Structure (fwd/bwd 2-wave split, LDS chunk staging, deferred renorm,
// band masks, slim reduce) unchanged from r15 (27.9us).

#define LOG2E 1.4426950408889634f
#define LN2d 0.69314718055994530942

constexpr int Bc = 16, Tc = 500, Sc = 100, Fc = 35;
constexpr int NPAIR = Bc * Fc;  // 560
constexpr int EXPB = 217;       // renorm target biased exponent (2^90)

__device__ __forceinline__ float dpp_shr1(float v) {  // lane l <- l-1, fill 0
  return __int_as_float(__builtin_amdgcn_update_dpp(
      0, __float_as_int(v), 0x138, 0xF, 0xF, false));
}
__device__ __forceinline__ float dpp_shl1(float v) {  // lane l <- l+1, fill 0
  return __int_as_float(__builtin_amdgcn_update_dpp(
      0, __float_as_int(v), 0x130, 0xF, 0xF, false));
}
template <int C>
__device__ __forceinline__ int dppmax(int v) {
  int t = __builtin_amdgcn_update_dpp(v, v, C, 0xF, 0xF, false);
  return max(v, t);
}

// 3-class softmax -> float4(q2, q0, q1-q0, 0); log2 domain
__device__ __forceinline__ float4 smf(float xr, float bl2) {
  const float x = xr * LOG2E;
  const float m = fmaxf(fabsf(x), bl2);
  const float u0 = exp2f(-x - m), u1 = exp2f(x - m), u2 = exp2f(bl2 - m);
  const float rz = 1.0f / (u0 + u1 + u2);
  return make_float4(u2 * rz, u0 * rz, (u1 - u0) * rz, 0.0f);
}

// One direction. BWD=false: alpha, t = tstart + i. BWD=true: beta,
// t = tstart - i. N steps. Lane l holds states 4l..4l+3 in a0..a3.
// skXf/skYf: own-lane skip flags; skNf/btNf: neighbor-lane skip/target
// (fwd: lane l-1's sk3/bt1; bwd: lane l+1's sk3/bt0) for the composite.
template <bool BWD>
__device__ __forceinline__ void scan_dir(
    const float* __restrict__ lg, float bl2, int Tin, int L, int N,
    int tstart, float bt0f, float bt1f, float skXf, float skYf, float skNf,
    float btNf, int lane, float4 (*stg)[64], float& A0, float& A1, float& A2,
    float& A3, int& offOut) {
  float a0 = A0, a1 = A1, a2 = A2, a3 = A3;
  int off = -90;
  int mm = 0;

  const int e_hi = 2 * L + 1, twoLm1 = 2 * L - 1;
  const int e0 = 4 * lane;
  const bool in0 = e0 <= e_hi, in1 = e0 + 1 <= e_hi, in2 = e0 + 2 <= e_hi,
             in3 = e0 + 3 <= e_hi;

  auto addr = [&](int i) -> int {  // step index -> clamped time index
    if (BWD) return max(tstart - i, 0);
    return min(tstart + i, Tc - 1);
  };

  // single step (tail only)
  auto step = [&](const float4& G) {
    const float po0 = fmaf(bt0f, G.z, G.y);
    const float po1 = fmaf(bt1f, G.z, G.y);
    if constexpr (!BWD) {
      const float pr3 = dpp_shr1(a3);
      const float s01 = a0 + a1, s12 = a1 + a2, s23 = a2 + a3;
      const float t0v = a0 + pr3;
      const float t1v = fmaf(pr3, skXf, s01);
      const float t3v = fmaf(a1, skYf, s23);
      a0 = t0v * G.x; a1 = t1v * po0; a2 = s12 * G.x; a3 = t3v * po1;
    } else {
      const float nb0 = dpp_shl1(a0);
      const float nb1 = dpp_shl1(a1);
      const float s01 = a0 + a1, s12 = a1 + a2, s23 = a2 + a3;
      const float t1v = fmaf(a3, skXf, s12);
      const float t3v = fmaf(nb1, skYf, a3 + nb0);
      a0 = s01 * G.x; a1 = t1v * po0; a2 = s23 * G.x; a3 = t3v * po1;
    }
  };

  // composed double step: probs GA (first), GB (second). Coefficients are
  // alpha-independent (shadow work); alpha path is one fma-tree of depth ~3.
  auto dstep = [&](const float4& GA, const float4& GB) {
    const float q2a = GA.x, q0a = GA.y, qda = GA.z;
    const float q2b = GB.x, q0b = GB.y, qdb = GB.z;
    const float poXa = fmaf(bt0f, qda, q0a);
    const float poYa = fmaf(bt1f, qda, q0a);
    const float poNa = fmaf(btNf, qda, q0a);
    const float poXb = fmaf(bt0f, qdb, q0b);
    const float poYb = fmaf(bt1f, qdb, q0b);
    if constexpr (!BWD) {
      const float P3 = dpp_shr1(a3);
      const float P2 = dpp_shr1(a2);
      const float P1 = dpp_shr1(a1);
      const float pNs = poNa * skNf;
      const float C00 = q2b * q2a;
      const float C0P3 = q2b * (q2a + poNa);
      const float C0P2 = q2b * poNa;
      const float C0P1 = q2b * pNs;
      const float C11 = poXb * poXa;
      const float C10 = poXb * (poXa + q2a);
      const float C1P3 = poXb * fmaf(skXf, poXa + poNa, q2a);
      const float s1pN = skXf * poNa;
      const float C1P2 = poXb * s1pN;
      const float C1P1 = poXb * (s1pN * skNf);
      const float C21 = q2b * (q2a + poXa);
      const float C20 = q2b * poXa;
      const float C2P3 = C20 * skXf;
      const float C33 = poYb * poYa;
      const float C32 = poYb * (poYa + q2a);
      const float C31 = poYb * fmaf(skYf, poYa + poXa, q2a);
      const float s3pX = skYf * poXa;
      const float C30 = poYb * s3pX;
      const float C3P = poYb * (s3pX * skXf);
      const float n0 = fmaf(C00, a0, C0P3 * P3) + fmaf(C0P2, P2, C0P1 * P1);
      const float n1 = fmaf(C11, a1, C10 * a0) +
                       fmaf(C1P3, P3, fmaf(C1P2, P2, C1P1 * P1));
      const float n2 = fmaf(C00, a2, C21 * a1) + fmaf(C20, a0, C2P3 * P3);
      const float n3 = fmaf(C33, a3, C32 * a2) +
                       fmaf(C31, a1, fmaf(C30, a0, C3P * P3));
      a0 = n0; a1 = n1; a2 = n2; a3 = n3;
    } else {
      const float N0 = dpp_shl1(a0);
      const float N1 = dpp_shl1(a1);
      const float N2 = dpp_shl1(a2);
      const float N3 = dpp_shl1(a3);
      const float D00 = q2b * q2a;
      const float D01 = q2b * (q2a + poXa);
      const float D02 = q2b * poXa;
      const float D03 = D02 * skXf;
      const float D11 = poXb * poXa;
      const float D12 = poXb * (poXa + q2a);
      const float D13 = poXb * fmaf(skXf, poXa + poYa, q2a);
      const float s3Y = skXf * poYa;
      const float D1N0 = poXb * s3Y;
      const float D1N1 = poXb * (s3Y * skYf);
      const float D23 = q2b * (q2a + poYa);
      const float D2N0 = q2b * poYa;
      const float D2N1 = D2N0 * skYf;
      const float D33 = poYb * poYa;
      const float D3N0 = poYb * (poYa + q2a);
      const float D3N1 = poYb * fmaf(skYf, poYa + poNa, q2a);
      const float w = skYf * poNa;
      const float D3N2 = poYb * w;
      const float D3N3 = poYb * (w * skNf);
      const float n0 = fmaf(D00, a0, D01 * a1) + fmaf(D02, a2, D03 * a3);
      const float n1 = fmaf(D11, a1, D12 * a2) +
                       fmaf(D13, a3, fmaf(D1N0, N0, D1N1 * N1));
      const float n2 = fmaf(D00, a2, D23 * a3) + fmaf(D2N0, N0, D2N1 * N1);
      const float n3 = fmaf(D33, a3, D3N0 * N0) +
                       fmaf(D3N1, N1, fmaf(D3N2, N2, D3N3 * N3));
      a0 = n0; a1 = n1; a2 = n2; a3 = n3;
    }
  };

  auto snap = [&](int istep) {
    if constexpr (!BWD) {
      const int t = tstart + istep;
      const int elo = twoLm1 - 2 * (Tin - 1 - t);
      const int x0 = (in0 && e0 >= elo) ? (__float_as_int(a0) >> 23) : 0;
      const int x1 = (in1 && e0 + 1 >= elo) ? (__float_as_int(a1) >> 23) : 0;
      const int x2 = (in2 && e0 + 2 >= elo) ? (__float_as_int(a2) >> 23) : 0;
      const int x3 = (in3 && e0 + 3 >= elo) ? (__float_as_int(a3) >> 23) : 0;
      mm = max(max(x0, x1), max(x2, x3));
    } else {
      (void)istep;  // beta: states > 2L are exactly 0, safe unmasked
      const int x0 = __float_as_int(a0) >> 23, x1 = __float_as_int(a1) >> 23;
      const int x2 = __float_as_int(a2) >> 23, x3 = __float_as_int(a3) >> 23;
      mm = max(max(x0, x1), max(x2, x3));
    }
  };
  auto tree = [&]() {
    mm = dppmax<0x111>(mm); mm = dppmax<0x112>(mm); mm = dppmax<0x114>(mm);
    mm = dppmax<0x118>(mm); mm = dppmax<0x142>(mm); mm = dppmax<0x143>(mm);
  };
  auto apply = [&]() {
    const int mw = __builtin_amdgcn_readlane(mm, 63);
    int k = EXPB - mw;
    k = min(max(k, -126), 126);
    const float sc = __int_as_float((k + 127) << 23);
    a0 *= sc; a1 *= sc; a2 *= sc; a3 *= sc;
    off -= k;
  };
  // 8 timesteps as 4 double-steps; prefetch next 8 float4s into Q.
  auto group = [&](float4 (&P)[8], float4 (&Q)[8], const float4* src,
                   int ilast) {
#pragma unroll
    for (int i = 0; i < 8; ++i) Q[i] = src[i];
    dstep(P[0], P[1]);
    tree();
    dstep(P[2], P[3]);
    apply();
    dstep(P[4], P[5]);
    dstep(P[6], P[7]);
    snap(ilast);
  };

  // prologue: stage chunk0, preload raw for chunk1, load group0, snapshot
  float xraw = lg[addr(lane) * Fc];
  stg[0][lane] = smf(xraw, bl2);
  xraw = lg[addr(64 + lane) * Fc];
  float4 A[8], B[8];
#pragma unroll
  for (int i = 0; i < 8; ++i) A[i] = stg[0][i];
  snap(-1);

  int buf = 0, ib = 0;
  for (; ib + 64 <= N; ib += 64) {
    if (ib + 64 < N) {
      stg[buf ^ 1][lane] = smf(xraw, bl2);
      xraw = lg[addr(ib + 128 + lane) * Fc];
    }
    const float4* cpA = &stg[buf][0];
    const float4* cpB = &stg[buf ^ 1][0];
#pragma unroll
    for (int d = 0; d < 4; ++d) {
      group(A, B, cpA + 8 * (2 * d + 1), ib + 16 * d + 7);
      group(B, A, (d < 3) ? (cpA + 8 * (2 * d + 2)) : cpB, ib + 16 * d + 15);
    }
    buf ^= 1;
  }
  {  // tail: n in [0,63] single steps, immediate renorm per 8
    const int n = N - ib;
    const float4* cp = &stg[buf][0];
#pragma unroll
    for (int grp = 0; grp < 8; ++grp) {
      if (8 * grp >= n) break;  // wave-uniform
      float4 g[8];
#pragma unroll
      for (int i = 0; i < 8; ++i) g[i] = cp[8 * grp + i];
#pragma unroll
      for (int i = 0; i < 8; ++i) {
        if (8 * grp + i >= n) break;  // wave-uniform
        step(g[i]);
      }
      if (8 * grp + 8 <= n) { snap(ib + 8 * grp + 7); tree(); apply(); }
    }
  }
  A0 = a0; A1 = a1; A2 = a2; A3 = a3;
  offOut = off;
}

__global__ __launch_bounds__(128) void sctc_scan(
    const float* __restrict__ logits,       // (B,T,F)
    const float* __restrict__ blank_logit,  // (1,)
    const int* __restrict__ targets,        // (B,S,F) 0/1
    const int* __restrict__ in_len,         // (B,)
    const int* __restrict__ tgt_len,        // (B,)
    float* __restrict__ part) {             // (NPAIR,)
  __shared__ float4 stg[2][2][64];  // [wave][dbuf][lane]
  __shared__ float4 xch[64];
  __shared__ int offsh;
  const int tid = threadIdx.x, wid = tid >> 6, lane = tid & 63;
  const int p = blockIdx.x;
  const int b = p / Fc, f = p - b * Fc;
  const int Tin = in_len[b];  // uniform
  const int L = tgt_len[b];   // uniform
  const float bl2 = blank_logit[0] * LOG2E;
  const float* __restrict__ lg = logits + (size_t)b * Tc * Fc + f;
  const float S90 = __int_as_float((90 + 127) << 23);
  const int e0 = 4 * lane;

  const int tbase = b * Sc * Fc + f;
  const int t0 = targets[tbase + min(2 * lane, Sc - 1) * Fc];
  const int t1 = targets[tbase + min(2 * lane + 1, Sc - 1) * Fc];
  const int tprev = __shfl_up(t1, 1);     // tgt[2l-1]
  const int tnext0 = __shfl_down(t0, 1);  // tgt[2l+2]
  const float bt0f = t0 ? 1.0f : 0.0f, bt1f = t1 ? 1.0f : 0.0f;
  const float sk1f = (lane == 0 || t0 != tprev) ? 1.0f : 0.0f;
  const float sk3f = (t1 != t0) ? 1.0f : 0.0f;
  const float skBf = (tnext0 != t1) ? 1.0f : 0.0f;

  const int tm = Tin >> 1;
  const int NF = tm;            // fwd steps: t = 1..tm
  const int NB = Tin - 2 - tm;  // bwd steps: t = Tin-2..tm+1

  float a0 = 0.0f, a1 = 0.0f, a2 = 0.0f, a3 = 0.0f;
  int off = -90;

  if (wid == 0) {  // forward alpha
    const float skNf = __shfl_up(sk3f, 1);  // prev lane's sk3 (lane0: unused)
    const float btNf = __shfl_up(bt1f, 1);  // prev lane's bt1
    const float4 c0 = smf(lg[0], bl2);
    if (lane == 0) {
      a0 = c0.x * S90;
      a1 = fmaf(bt0f, c0.z, c0.y) * S90;
    }
    scan_dir<false>(lg, bl2, Tin, L, NF, 1, bt0f, bt1f, sk1f, sk3f, skNf,
                    btNf, lane, stg[0], a0, a1, a2, a3, off);
  } else {  // backward beta
    const float skNf = __shfl_down(sk3f, 1);  // next lane's sk3
    const float btNf = __shfl_down(bt0f, 1);  // next lane's bt0
    const float4 cE = smf(lg[(Tin - 1) * Fc], bl2);
    if (e0 == 2 * L) a0 = cE.x * S90;
    if (e0 + 2 == 2 * L) a2 = cE.x * S90;
    if (e0 + 1 == 2 * L - 1) a1 = fmaf(bt0f, cE.z, cE.y) * S90;
    if (e0 + 3 == 2 * L - 1) a3 = fmaf(bt1f, cE.z, cE.y) * S90;
    scan_dir<true>(lg, bl2, Tin, L, NB, Tin - 2, bt0f, bt1f, sk3f, skBf,
                   skNf, btNf, lane, stg[1], a0, a1, a2, a3, off);
    // gamma half-step: transition sum of beta_{tm+1} without emission probs
    const float nb0 = dpp_shl1(a0), nb1 = dpp_shl1(a1);
    const float bt0v = a0 + a1;
    const float bt1v = fmaf(a3, sk3f, a1 + a2);
    const float bt2v = a2 + a3;
    const float bt3v = fmaf(nb1, skBf, a3 + nb0);
    xch[lane] = make_float4(bt0v, bt1v, bt2v, bt3v);
    if (lane == 0) offsh = off;
  }
  __syncthreads();
  if (wid == 0) {
    const float4 bb = xch[lane];
    // mask alpha to e <= 2L (inf guard; gamma is exactly 0 there).
    const int twoL = 2 * L;
    const float z0 = (e0 <= twoL) ? a0 : 0.0f;
    const float z1 = (e0 + 1 <= twoL) ? a1 : 0.0f;
    const float z2 = (e0 + 2 <= twoL) ? a2 : 0.0f;
    const float z3 = (e0 + 3 <= twoL) ? a3 : 0.0f;
    double d = (double)z0 * bb.x + (double)z1 * bb.y + (double)z2 * bb.z +
               (double)z3 * bb.w;
    for (int o = 32; o >= 1; o >>= 1) d += __shfl_down(d, o);
    if (lane == 0) {
      const int offT = off + offsh;
      float val = 0.0f;
      if (d > 0.0) {
        int ex;
        const double mant = frexp(d, &ex);
        const double ll2 = (double)(ex + offT) + log2(mant);
        double ld = -ll2 * LN2d;
        if (ld > 0.5e30) ld = 0.0;  // zero_infinity
        val = (float)(ld / (double)L) * (1.0f / (float)NPAIR);
      }
      part[p] = val;
    }
  }
}

// Slim reduce: 1 wave, 9 batched independent loads, fixed-order sum +
// fixed shuffle tree -> bit-deterministic.
__global__ __launch_bounds__(64) void sctc_reduce(const float* __restrict__ ws,
                                                  float* __restrict__ out) {
  const int lane = threadIdx.x;
  const float v0 = ws[lane];
  const float v1 = ws[lane + 64];
  const float v2 = ws[lane + 128];
  const float v3 = ws[lane + 192];
  const float v4 = ws[lane + 256];
  const float v5 = ws[lane + 320];
  const float v6 = ws[lane + 384];
  const float v7 = ws[lane + 448];
  float v8 = ws[(lane < 48) ? (lane + 512) : lane];
  if (lane >= 48) v8 = 0.0f;
  float s = ((((((((v0 + v1) + v2) + v3) + v4) + v5) + v6) + v7) + v8);
  for (int o = 32; o >= 1; o >>= 1) s += __shfl_xor(s, o);
  if (lane == 0) out[0] = s;
}

extern "C" void kernel_launch(void* const* d_in, const int* in_sizes, int n_in,
                              void* d_out, int out_size, void* d_ws,
                              size_t ws_size, hipStream_t stream) {
  const float* logits = (const float*)d_in[0];
  const float* blank_logit = (const float*)d_in[1];
  const int* targets = (const int*)d_in[2];
  const int* in_len = (const int*)d_in[3];
  const int* tgt_len = (const int*)d_in[4];
  float* part = (float*)d_ws;
  float* out = (float*)d_out;

  sctc_scan<<<NPAIR, 128, 0, stream>>>(logits, blank_logit, targets, in_len,
                                       tgt_len, part);
  sctc_reduce<<<1, 64, 0, stream>>>(part, out);
}

// Round 17
// 27.752 us; speedup vs baseline: 1.3534x; 1.3534x over previous
//
#include <hip/hip_runtime.h>
#include <math.h>

// SCTC-SB loss, round 17 = round 15 VERBATIM (best measured: 27.88us).
// r16's double-step regression (+35%, proportional to added issue work)
// falsified the latency-bound model: the scan is issue/overhead-bound, so
// only instruction-count reductions win. r15 is the minimum-instruction
// variant found: fwd/bwd 2-wave split, 13 VALU/step linear-domain recursion,
// 1 DPP/step, LDS-staged per-chunk softmax, deferred renorm, slim reduce.

#define LOG2E 1.4426950408889634f
#define LN2d 0.69314718055994530942

constexpr int Bc = 16, Tc = 500, Sc = 100, Fc = 35;
constexpr int NPAIR = Bc * Fc;  // 560
constexpr int EXPB = 217;       // renorm target biased exponent (2^90)

__device__ __forceinline__ float dpp_shr1(float v) {  // lane l <- l-1, fill 0
  return __int_as_float(__builtin_amdgcn_update_dpp(
      0, __float_as_int(v), 0x138, 0xF, 0xF, false));
}
__device__ __forceinline__ float dpp_shl1(float v) {  // lane l <- l+1, fill 0
  return __int_as_float(__builtin_amdgcn_update_dpp(
      0, __float_as_int(v), 0x130, 0xF, 0xF, false));
}
template <int C>
__device__ __forceinline__ int dppmax(int v) {
  int t = __builtin_amdgcn_update_dpp(v, v, C, 0xF, 0xF, false);
  return max(v, t);
}

// 3-class softmax -> float4(q2, q0, q1-q0, 0); log2 domain
__device__ __forceinline__ float4 smf(float xr, float bl2) {
  const float x = xr * LOG2E;
  const float m = fmaxf(fabsf(x), bl2);
  const float u0 = exp2f(-x - m), u1 = exp2f(x - m), u2 = exp2f(bl2 - m);
  const float rz = 1.0f / (u0 + u1 + u2);
  return make_float4(u2 * rz, u0 * rz, (u1 - u0) * rz, 0.0f);
}

// One direction of the scan. BWD=false: alpha, t = tstart + i (tstart=1).
// BWD=true: beta, t = tstart - i (tstart=Tin-2). N steps. States in
// a0..a3 (lane l holds e=4l..4l+3), pre-initialized by caller at scale 2^90.
template <bool BWD>
__device__ __forceinline__ void scan_dir(
    const float* __restrict__ lg, float bl2, int Tin, int L, int N,
    int tstart, float bt0f, float bt1f, float skXf, float skYf, int lane,
    float4 (*stg)[64], float& A0, float& A1, float& A2, float& A3,
    int& offOut) {
  float a0 = A0, a1 = A1, a2 = A2, a3 = A3;
  int off = -90;
  int mm = 0;

  const int e_hi = 2 * L + 1, twoLm1 = 2 * L - 1;
  const int e0 = 4 * lane;
  const bool in0 = e0 <= e_hi, in1 = e0 + 1 <= e_hi, in2 = e0 + 2 <= e_hi,
             in3 = e0 + 3 <= e_hi;

  auto addr = [&](int i) -> int {  // step index -> clamped time index
    if (BWD) return max(tstart - i, 0);
    return min(tstart + i, Tc - 1);
  };

  auto step = [&](const float4& G) {
    const float po0 = fmaf(bt0f, G.z, G.y);
    const float po1 = fmaf(bt1f, G.z, G.y);
    if constexpr (!BWD) {
      const float pr3 = dpp_shr1(a3);  // alpha[4l-1]
      const float s01 = a0 + a1, s12 = a1 + a2, s23 = a2 + a3;
      const float t0v = a0 + pr3;
      const float t1v = fmaf(pr3, skXf, s01);
      const float t3v = fmaf(a1, skYf, s23);
      a0 = t0v * G.x; a1 = t1v * po0; a2 = s12 * G.x; a3 = t3v * po1;
    } else {
      const float nb0 = dpp_shl1(a0);  // beta[4l+4]
      const float nb1 = dpp_shl1(a1);  // beta[4l+5]
      const float s01 = a0 + a1, s12 = a1 + a2, s23 = a2 + a3;
      const float t1v = fmaf(a3, skXf, s12);
      const float t3v = fmaf(nb1, skYf, a3 + nb0);
      a0 = s01 * G.x; a1 = t1v * po0; a2 = s23 * G.x; a3 = t3v * po1;
    }
  };

  auto snap = [&](int istep) {
    if constexpr (!BWD) {
      const int t = tstart + istep;
      const int elo = twoLm1 - 2 * (Tin - 1 - t);
      const int x0 = (in0 && e0 >= elo) ? (__float_as_int(a0) >> 23) : 0;
      const int x1 = (in1 && e0 + 1 >= elo) ? (__float_as_int(a1) >> 23) : 0;
      const int x2 = (in2 && e0 + 2 >= elo) ? (__float_as_int(a2) >> 23) : 0;
      const int x3 = (in3 && e0 + 3 >= elo) ? (__float_as_int(a3) >> 23) : 0;
      mm = max(max(x0, x1), max(x2, x3));
    } else {
      (void)istep;  // beta: states > 2L are exactly 0, safe unmasked
      const int x0 = __float_as_int(a0) >> 23, x1 = __float_as_int(a1) >> 23;
      const int x2 = __float_as_int(a2) >> 23, x3 = __float_as_int(a3) >> 23;
      mm = max(max(x0, x1), max(x2, x3));
    }
  };
  auto tree = [&]() {
    mm = dppmax<0x111>(mm); mm = dppmax<0x112>(mm); mm = dppmax<0x114>(mm);
    mm = dppmax<0x118>(mm); mm = dppmax<0x142>(mm); mm = dppmax<0x143>(mm);
  };
  auto apply = [&]() {
    const int mw = __builtin_amdgcn_readlane(mm, 63);
    int k = EXPB - mw;
    k = min(max(k, -126), 126);
    const float sc = __int_as_float((k + 127) << 23);
    a0 *= sc; a1 *= sc; a2 *= sc; a3 *= sc;
    off -= k;
  };
  auto group = [&](float4 (&P)[8], float4 (&Q)[8], const float4* src,
                   int ilast) {
#pragma unroll
    for (int i = 0; i < 8; ++i) Q[i] = src[i];
    step(P[0]);
    tree();
    step(P[1]); step(P[2]); step(P[3]);
    apply();
    step(P[4]); step(P[5]); step(P[6]); step(P[7]);
    snap(ilast);
  };

  // prologue: stage chunk0, preload raw for chunk1, load group0, snapshot
  float xraw = lg[addr(lane) * Fc];
  stg[0][lane] = smf(xraw, bl2);
  xraw = lg[addr(64 + lane) * Fc];
  float4 A[8], B[8];
#pragma unroll
  for (int i = 0; i < 8; ++i) A[i] = stg[0][i];
  snap(-1);

  int buf = 0, ib = 0;
  for (; ib + 64 <= N; ib += 64) {
    if (ib + 64 < N) {
      stg[buf ^ 1][lane] = smf(xraw, bl2);
      xraw = lg[addr(ib + 128 + lane) * Fc];
    }
    const float4* cpA = &stg[buf][0];
    const float4* cpB = &stg[buf ^ 1][0];
#pragma unroll
    for (int d = 0; d < 4; ++d) {
      group(A, B, cpA + 8 * (2 * d + 1), ib + 16 * d + 7);
      group(B, A, (d < 3) ? (cpA + 8 * (2 * d + 2)) : cpB, ib + 16 * d + 15);
    }
    buf ^= 1;
  }
  {  // tail: n in [0,63], immediate renorm per 8
    const int n = N - ib;
    const float4* cp = &stg[buf][0];
#pragma unroll
    for (int grp = 0; grp < 8; ++grp) {
      if (8 * grp >= n) break;  // wave-uniform
      float4 g[8];
#pragma unroll
      for (int i = 0; i < 8; ++i) g[i] = cp[8 * grp + i];
#pragma unroll
      for (int i = 0; i < 8; ++i) {
        if (8 * grp + i >= n) break;  // wave-uniform
        step(g[i]);
      }
      if (8 * grp + 8 <= n) { snap(ib + 8 * grp + 7); tree(); apply(); }
    }
  }
  A0 = a0; A1 = a1; A2 = a2; A3 = a3;
  offOut = off;
}

__global__ __launch_bounds__(128) void sctc_scan(
    const float* __restrict__ logits,       // (B,T,F)
    const float* __restrict__ blank_logit,  // (1,)
    const int* __restrict__ targets,        // (B,S,F) 0/1
    const int* __restrict__ in_len,         // (B,)
    const int* __restrict__ tgt_len,        // (B,)
    float* __restrict__ part) {             // (NPAIR,)
  __shared__ float4 stg[2][2][64];  // [wave][dbuf][lane]
  __shared__ float4 xch[64];
  __shared__ int offsh;
  const int tid = threadIdx.x, wid = tid >> 6, lane = tid & 63;
  const int p = blockIdx.x;
  const int b = p / Fc, f = p - b * Fc;
  const int Tin = in_len[b];  // uniform
  const int L = tgt_len[b];   // uniform
  const float bl2 = blank_logit[0] * LOG2E;
  const float* __restrict__ lg = logits + (size_t)b * Tc * Fc + f;
  const float S90 = __int_as_float((90 + 127) << 23);
  const int e0 = 4 * lane;

  const int tbase = b * Sc * Fc + f;
  const int t0 = targets[tbase + min(2 * lane, Sc - 1) * Fc];
  const int t1 = targets[tbase + min(2 * lane + 1, Sc - 1) * Fc];
  const int tprev = __shfl_up(t1, 1);     // tgt[2l-1]
  const int tnext0 = __shfl_down(t0, 1);  // tgt[2l+2]
  const float bt0f = t0 ? 1.0f : 0.0f, bt1f = t1 ? 1.0f : 0.0f;
  const float sk1f = (lane == 0 || t0 != tprev) ? 1.0f : 0.0f;
  const float sk3f = (t1 != t0) ? 1.0f : 0.0f;
  const float skBf = (tnext0 != t1) ? 1.0f : 0.0f;

  const int tm = Tin >> 1;
  const int NF = tm;            // fwd steps: t = 1..tm
  const int NB = Tin - 2 - tm;  // bwd steps: t = Tin-2..tm+1

  float a0 = 0.0f, a1 = 0.0f, a2 = 0.0f, a3 = 0.0f;
  int off = -90;

  if (wid == 0) {  // forward alpha
    const float4 c0 = smf(lg[0], bl2);
    if (lane == 0) {
      a0 = c0.x * S90;
      a1 = fmaf(bt0f, c0.z, c0.y) * S90;
    }
    scan_dir<false>(lg, bl2, Tin, L, NF, 1, bt0f, bt1f, sk1f, sk3f, lane,
                    stg[0], a0, a1, a2, a3, off);
  } else {  // backward beta
    const float4 cE = smf(lg[(Tin - 1) * Fc], bl2);
    if (e0 == 2 * L) a0 = cE.x * S90;
    if (e0 + 2 == 2 * L) a2 = cE.x * S90;
    if (e0 + 1 == 2 * L - 1) a1 = fmaf(bt0f, cE.z, cE.y) * S90;
    if (e0 + 3 == 2 * L - 1) a3 = fmaf(bt1f, cE.z, cE.y) * S90;
    scan_dir<true>(lg, bl2, Tin, L, NB, Tin - 2, bt0f, bt1f, sk3f, skBf,
                   lane, stg[1], a0, a1, a2, a3, off);
    // gamma half-step: transition sum of beta_{tm+1} without emission probs
    const float nb0 = dpp_shl1(a0), nb1 = dpp_shl1(a1);
    const float bt0v = a0 + a1;
    const float bt1v = fmaf(a3, sk3f, a1 + a2);
    const float bt2v = a2 + a3;
    const float bt3v = fmaf(nb1, skBf, a3 + nb0);
    xch[lane] = make_float4(bt0v, bt1v, bt2v, bt3v);
    if (lane == 0) offsh = off;
  }
  __syncthreads();
  if (wid == 0) {
    const float4 bb = xch[lane];
    // mask alpha to e <= 2L: out-of-band alphas may be +inf (excluded from
    // renorm max by design); gamma there is exactly 0; inf*0 = NaN guard.
    const int twoL = 2 * L;
    const float z0 = (e0 <= twoL) ? a0 : 0.0f;
    const float z1 = (e0 + 1 <= twoL) ? a1 : 0.0f;
    const float z2 = (e0 + 2 <= twoL) ? a2 : 0.0f;
    const float z3 = (e0 + 3 <= twoL) ? a3 : 0.0f;
    double d = (double)z0 * bb.x + (double)z1 * bb.y + (double)z2 * bb.z +
               (double)z3 * bb.w;
    for (int o = 32; o >= 1; o >>= 1) d += __shfl_down(d, o);
    if (lane == 0) {
      const int offT = off + offsh;
      float val = 0.0f;
      if (d > 0.0) {
        int ex;
        const double mant = frexp(d, &ex);
        const double ll2 = (double)(ex + offT) + log2(mant);
        double ld = -ll2 * LN2d;
        if (ld > 0.5e30) ld = 0.0;  // zero_infinity
        val = (float)(ld / (double)L) * (1.0f / (float)NPAIR);
      }
      part[p] = val;
    }
  }
}

// Slim reduce: 1 wave, 9 batched independent loads (no loop-carried dep),
// fixed-order sum + fixed shuffle tree -> bit-deterministic. Kernel boundary
// guarantees visibility of part[] (no atomics/fences needed).
__global__ __launch_bounds__(64) void sctc_reduce(const float* __restrict__ ws,
                                                  float* __restrict__ out) {
  const int lane = threadIdx.x;
  const float v0 = ws[lane];
  const float v1 = ws[lane + 64];
  const float v2 = ws[lane + 128];
  const float v3 = ws[lane + 192];
  const float v4 = ws[lane + 256];
  const float v5 = ws[lane + 320];
  const float v6 = ws[lane + 384];
  const float v7 = ws[lane + 448];
  float v8 = ws[(lane < 48) ? (lane + 512) : lane];
  if (lane >= 48) v8 = 0.0f;
  float s = ((((((((v0 + v1) + v2) + v3) + v4) + v5) + v6) + v7) + v8);
  for (int o = 32; o >= 1; o >>= 1) s += __shfl_xor(s, o);
  if (lane == 0) out[0] = s;
}

extern "C" void kernel_launch(void* const* d_in, const int* in_sizes, int n_in,
                              void* d_out, int out_size, void* d_ws,
                              size_t ws_size, hipStream_t stream) {
  const float* logits = (const float*)d_in[0];
  const float* blank_logit = (const float*)d_in[1];
  const int* targets = (const int*)d_in[2];
  const int* in_len = (const int*)d_in[3];
  const int* tgt_len = (const int*)d_in[4];
  float* part = (float*)d_ws;
  float* out = (float*)d_out;

  sctc_scan<<<NPAIR, 128, 0, stream>>>(logits, blank_logit, targets, in_len,
                                       tgt_len, part);
  sctc_reduce<<<1, 64, 0, stream>>>(part, out);
}

// Round 18
// 25.154 us; speedup vs baseline: 1.4932x; 1.1033x over previous
//
#include <hip/hip_runtime.h>
#include <math.h>

// SCTC-SB loss, round 18 = round 15 + renorm cadence 8 -> 32 steps:
// renorm (snap/tree/apply) was ~3 ops/step (~18% of issue); now 1 renorm per
// 32 steps (snap at chunk steps 32/64; tree+apply early in following group).
// Scale target lowered 2^90 -> 2^56: growth bound <= log2(3)/step keeps
// in-band max <= 2^113 < 2^128 between applies (provable); decay budget
// 56+126=182 bits vs ~55-bit typical 32-step drift (empirical, underflow of
// sub-dominant states is accuracy-harmless). Tail keeps 8-step renorm.

#define LOG2E 1.4426950408889634f
#define LN2d 0.69314718055994530942

constexpr int Bc = 16, Tc = 500, Sc = 100, Fc = 35;
constexpr int NPAIR = Bc * Fc;  // 560
constexpr int INIT_E = 56;            // working scale 2^56
constexpr int EXPB = INIT_E + 127;    // renorm target biased exponent

__device__ __forceinline__ float dpp_shr1(float v) {  // lane l <- l-1, fill 0
  return __int_as_float(__builtin_amdgcn_update_dpp(
      0, __float_as_int(v), 0x138, 0xF, 0xF, false));
}
__device__ __forceinline__ float dpp_shl1(float v) {  // lane l <- l+1, fill 0
  return __int_as_float(__builtin_amdgcn_update_dpp(
      0, __float_as_int(v), 0x130, 0xF, 0xF, false));
}
template <int C>
__device__ __forceinline__ int dppmax(int v) {
  int t = __builtin_amdgcn_update_dpp(v, v, C, 0xF, 0xF, false);
  return max(v, t);
}

// 3-class softmax -> float4(q2, q0, q1-q0, 0); log2 domain
__device__ __forceinline__ float4 smf(float xr, float bl2) {
  const float x = xr * LOG2E;
  const float m = fmaxf(fabsf(x), bl2);
  const float u0 = exp2f(-x - m), u1 = exp2f(x - m), u2 = exp2f(bl2 - m);
  const float rz = 1.0f / (u0 + u1 + u2);
  return make_float4(u2 * rz, u0 * rz, (u1 - u0) * rz, 0.0f);
}

// One direction of the scan. BWD=false: alpha, t = tstart + i (tstart=1).
// BWD=true: beta, t = tstart - i (tstart=Tin-2). N steps. States in
// a0..a3 (lane l holds e=4l..4l+3), pre-initialized by caller at 2^INIT_E.
template <bool BWD>
__device__ __forceinline__ void scan_dir(
    const float* __restrict__ lg, float bl2, int Tin, int L, int N,
    int tstart, float bt0f, float bt1f, float skXf, float skYf, int lane,
    float4 (*stg)[64], float& A0, float& A1, float& A2, float& A3,
    int& offOut) {
  float a0 = A0, a1 = A1, a2 = A2, a3 = A3;
  int off = -INIT_E;
  int mm = 0;

  const int e_hi = 2 * L + 1, twoLm1 = 2 * L - 1;
  const int e0 = 4 * lane;
  const bool in0 = e0 <= e_hi, in1 = e0 + 1 <= e_hi, in2 = e0 + 2 <= e_hi,
             in3 = e0 + 3 <= e_hi;

  auto addr = [&](int i) -> int {  // step index -> clamped time index
    if (BWD) return max(tstart - i, 0);
    return min(tstart + i, Tc - 1);
  };

  auto step = [&](const float4& G) {
    const float po0 = fmaf(bt0f, G.z, G.y);
    const float po1 = fmaf(bt1f, G.z, G.y);
    if constexpr (!BWD) {
      const float pr3 = dpp_shr1(a3);  // alpha[4l-1]
      const float s01 = a0 + a1, s12 = a1 + a2, s23 = a2 + a3;
      const float t0v = a0 + pr3;
      const float t1v = fmaf(pr3, skXf, s01);
      const float t3v = fmaf(a1, skYf, s23);
      a0 = t0v * G.x; a1 = t1v * po0; a2 = s12 * G.x; a3 = t3v * po1;
    } else {
      const float nb0 = dpp_shl1(a0);  // beta[4l+4]
      const float nb1 = dpp_shl1(a1);  // beta[4l+5]
      const float s01 = a0 + a1, s12 = a1 + a2, s23 = a2 + a3;
      const float t1v = fmaf(a3, skXf, s12);
      const float t3v = fmaf(nb1, skYf, a3 + nb0);
      a0 = s01 * G.x; a1 = t1v * po0; a2 = s23 * G.x; a3 = t3v * po1;
    }
  };

  auto snap = [&](int istep) {
    if constexpr (!BWD) {
      const int t = tstart + istep;
      const int elo = twoLm1 - 2 * (Tin - 1 - t);
      const int x0 = (in0 && e0 >= elo) ? (__float_as_int(a0) >> 23) : 0;
      const int x1 = (in1 && e0 + 1 >= elo) ? (__float_as_int(a1) >> 23) : 0;
      const int x2 = (in2 && e0 + 2 >= elo) ? (__float_as_int(a2) >> 23) : 0;
      const int x3 = (in3 && e0 + 3 >= elo) ? (__float_as_int(a3) >> 23) : 0;
      mm = max(max(x0, x1), max(x2, x3));
    } else {
      (void)istep;  // beta: states > 2L are exactly 0, safe unmasked
      const int x0 = __float_as_int(a0) >> 23, x1 = __float_as_int(a1) >> 23;
      const int x2 = __float_as_int(a2) >> 23, x3 = __float_as_int(a3) >> 23;
      mm = max(max(x0, x1), max(x2, x3));
    }
  };
  auto tree = [&]() {
    mm = dppmax<0x111>(mm); mm = dppmax<0x112>(mm); mm = dppmax<0x114>(mm);
    mm = dppmax<0x118>(mm); mm = dppmax<0x142>(mm); mm = dppmax<0x143>(mm);
  };
  auto apply = [&]() {
    const int mw = __builtin_amdgcn_readlane(mm, 63);
    int k = EXPB - mw;
    k = min(max(k, -126), 126);
    const float sc = __int_as_float((k + 127) << 23);
    a0 *= sc; a1 *= sc; a2 *= sc; a3 *= sc;
    off -= k;
  };
  // 8 steps from P, prefetch into Q. doTA: run tree early + apply mid-group
  // (on the most recent snapshot). doSnap: take a snapshot at group end.
  auto group = [&](float4 (&P)[8], float4 (&Q)[8], const float4* src,
                   int ilast, bool doTA, bool doSnap) {
#pragma unroll
    for (int i = 0; i < 8; ++i) Q[i] = src[i];
    step(P[0]);
    if (doTA) tree();
    step(P[1]); step(P[2]); step(P[3]);
    if (doTA) apply();
    step(P[4]); step(P[5]); step(P[6]); step(P[7]);
    if (doSnap) snap(ilast);
  };

  // prologue: stage chunk0, preload raw for chunk1, load group0, snapshot
  float xraw = lg[addr(lane) * Fc];
  stg[0][lane] = smf(xraw, bl2);
  xraw = lg[addr(64 + lane) * Fc];
  float4 A[8], B[8];
#pragma unroll
  for (int i = 0; i < 8; ++i) A[i] = stg[0][i];
  snap(-1);

  int buf = 0, ib = 0;
  for (; ib + 64 <= N; ib += 64) {
    if (ib + 64 < N) {
      stg[buf ^ 1][lane] = smf(xraw, bl2);
      xraw = lg[addr(ib + 128 + lane) * Fc];
    }
    const float4* cpA = &stg[buf][0];
    const float4* cpB = &stg[buf ^ 1][0];
    // renorm cadence 32: TA in groups 0 and 4; snap at ends of groups 3, 7.
#pragma unroll
    for (int d = 0; d < 4; ++d) {
      group(A, B, cpA + 8 * (2 * d + 1), ib + 16 * d + 7,
            (d == 0) || (d == 2), false);
      group(B, A, (d < 3) ? (cpA + 8 * (2 * d + 2)) : cpB, ib + 16 * d + 15,
            false, (d == 1) || (d == 3));
    }
    buf ^= 1;
  }
  {  // tail: n in [0,63], immediate renorm per 8
    const int n = N - ib;
    const float4* cp = &stg[buf][0];
#pragma unroll
    for (int grp = 0; grp < 8; ++grp) {
      if (8 * grp >= n) break;  // wave-uniform
      float4 g[8];
#pragma unroll
      for (int i = 0; i < 8; ++i) g[i] = cp[8 * grp + i];
#pragma unroll
      for (int i = 0; i < 8; ++i) {
        if (8 * grp + i >= n) break;  // wave-uniform
        step(g[i]);
      }
      if (8 * grp + 8 <= n) { snap(ib + 8 * grp + 7); tree(); apply(); }
    }
  }
  A0 = a0; A1 = a1; A2 = a2; A3 = a3;
  offOut = off;
}

__global__ __launch_bounds__(128) void sctc_scan(
    const float* __restrict__ logits,       // (B,T,F)
    const float* __restrict__ blank_logit,  // (1,)
    const int* __restrict__ targets,        // (B,S,F) 0/1
    const int* __restrict__ in_len,         // (B,)
    const int* __restrict__ tgt_len,        // (B,)
    float* __restrict__ part) {             // (NPAIR,)
  __shared__ float4 stg[2][2][64];  // [wave][dbuf][lane]
  __shared__ float4 xch[64];
  __shared__ int offsh;
  const int tid = threadIdx.x, wid = tid >> 6, lane = tid & 63;
  const int p = blockIdx.x;
  const int b = p / Fc, f = p - b * Fc;
  const int Tin = in_len[b];  // uniform
  const int L = tgt_len[b];   // uniform
  const float bl2 = blank_logit[0] * LOG2E;
  const float* __restrict__ lg = logits + (size_t)b * Tc * Fc + f;
  const float SINI = __int_as_float((INIT_E + 127) << 23);  // 2^INIT_E
  const int e0 = 4 * lane;

  const int tbase = b * Sc * Fc + f;
  const int t0 = targets[tbase + min(2 * lane, Sc - 1) * Fc];
  const int t1 = targets[tbase + min(2 * lane + 1, Sc - 1) * Fc];
  const int tprev = __shfl_up(t1, 1);     // tgt[2l-1]
  const int tnext0 = __shfl_down(t0, 1);  // tgt[2l+2]
  const float bt0f = t0 ? 1.0f : 0.0f, bt1f = t1 ? 1.0f : 0.0f;
  const float sk1f = (lane == 0 || t0 != tprev) ? 1.0f : 0.0f;
  const float sk3f = (t1 != t0) ? 1.0f : 0.0f;
  const float skBf = (tnext0 != t1) ? 1.0f : 0.0f;

  const int tm = Tin >> 1;
  const int NF = tm;            // fwd steps: t = 1..tm
  const int NB = Tin - 2 - tm;  // bwd steps: t = Tin-2..tm+1

  float a0 = 0.0f, a1 = 0.0f, a2 = 0.0f, a3 = 0.0f;
  int off = -INIT_E;

  if (wid == 0) {  // forward alpha
    const float4 c0 = smf(lg[0], bl2);
    if (lane == 0) {
      a0 = c0.x * SINI;
      a1 = fmaf(bt0f, c0.z, c0.y) * SINI;
    }
    scan_dir<false>(lg, bl2, Tin, L, NF, 1, bt0f, bt1f, sk1f, sk3f, lane,
                    stg[0], a0, a1, a2, a3, off);
  } else {  // backward beta
    const float4 cE = smf(lg[(Tin - 1) * Fc], bl2);
    if (e0 == 2 * L) a0 = cE.x * SINI;
    if (e0 + 2 == 2 * L) a2 = cE.x * SINI;
    if (e0 + 1 == 2 * L - 1) a1 = fmaf(bt0f, cE.z, cE.y) * SINI;
    if (e0 + 3 == 2 * L - 1) a3 = fmaf(bt1f, cE.z, cE.y) * SINI;
    scan_dir<true>(lg, bl2, Tin, L, NB, Tin - 2, bt0f, bt1f, sk3f, skBf,
                   lane, stg[1], a0, a1, a2, a3, off);
    // gamma half-step: transition sum of beta_{tm+1} without emission probs
    const float nb0 = dpp_shl1(a0), nb1 = dpp_shl1(a1);
    const float bt0v = a0 + a1;
    const float bt1v = fmaf(a3, sk3f, a1 + a2);
    const float bt2v = a2 + a3;
    const float bt3v = fmaf(nb1, skBf, a3 + nb0);
    xch[lane] = make_float4(bt0v, bt1v, bt2v, bt3v);
    if (lane == 0) offsh = off;
  }
  __syncthreads();
  if (wid == 0) {
    const float4 bb = xch[lane];
    // mask alpha to e <= 2L: out-of-band alphas may be +inf (excluded from
    // renorm max by design); gamma there is exactly 0; inf*0 = NaN guard.
    const int twoL = 2 * L;
    const float z0 = (e0 <= twoL) ? a0 : 0.0f;
    const float z1 = (e0 + 1 <= twoL) ? a1 : 0.0f;
    const float z2 = (e0 + 2 <= twoL) ? a2 : 0.0f;
    const float z3 = (e0 + 3 <= twoL) ? a3 : 0.0f;
    double d = (double)z0 * bb.x + (double)z1 * bb.y + (double)z2 * bb.z +
               (double)z3 * bb.w;
    for (int o = 32; o >= 1; o >>= 1) d += __shfl_down(d, o);
    if (lane == 0) {
      const int offT = off + offsh;
      float val = 0.0f;
      if (d > 0.0) {
        int ex;
        const double mant = frexp(d, &ex);
        const double ll2 = (double)(ex + offT) + log2(mant);
        double ld = -ll2 * LN2d;
        if (ld > 0.5e30) ld = 0.0;  // zero_infinity
        val = (float)(ld / (double)L) * (1.0f / (float)NPAIR);
      }
      part[p] = val;
    }
  }
}

// Slim reduce: 1 wave, 9 batched independent loads (no loop-carried dep),
// fixed-order sum + fixed shuffle tree -> bit-deterministic.
__global__ __launch_bounds__(64) void sctc_reduce(const float* __restrict__ ws,
                                                  float* __restrict__ out) {
  const int lane = threadIdx.x;
  const float v0 = ws[lane];
  const float v1 = ws[lane + 64];
  const float v2 = ws[lane + 128];
  const float v3 = ws[lane + 192];
  const float v4 = ws[lane + 256];
  const float v5 = ws[lane + 320];
  const float v6 = ws[lane + 384];
  const float v7 = ws[lane + 448];
  float v8 = ws[(lane < 48) ? (lane + 512) : lane];
  if (lane >= 48) v8 = 0.0f;
  float s = ((((((((v0 + v1) + v2) + v3) + v4) + v5) + v6) + v7) + v8);
  for (int o = 32; o >= 1; o >>= 1) s += __shfl_xor(s, o);
  if (lane == 0) out[0] = s;
}

extern "C" void kernel_launch(void* const* d_in, const int* in_sizes, int n_in,
                              void* d_out, int out_size, void* d_ws,
                              size_t ws_size, hipStream_t stream) {
  const float* logits = (const float*)d_in[0];
  const float* blank_logit = (const float*)d_in[1];
  const int* targets = (const int*)d_in[2];
  const int* in_len = (const int*)d_in[3];
  const int* tgt_len = (const int*)d_in[4];
  float* part = (float*)d_ws;
  float* out = (float*)d_out;

  sctc_scan<<<NPAIR, 128, 0, stream>>>(logits, blank_logit, targets, in_len,
                                       tgt_len, part);
  sctc_reduce<<<1, 64, 0, stream>>>(part, out);
}

// Round 19
// 22.268 us; speedup vs baseline: 1.6867x; 1.1296x over previous
//
#include <hip/hip_runtime.h>
#include <math.h>

// SCTC-SB loss, round 19 = round 18 + PACKED FP32 (VOP3P) recursion:
// states as two float2s u=(a0,a2), v=(a1,a3); step becomes ~6 v_pk_* ops
// (one instruction = 2 lanes' worth of fp32) + 1-2 DPP. Same fp operation
// sequence as scalar form -> bit-identical results. Renorm cadence 32,
// target 2^56, fwd/bwd 2-wave split, LDS chunk staging, slim reduce: as r18.

#define LOG2E 1.4426950408889634f
#define LN2d 0.69314718055994530942

typedef float f32x2 __attribute__((ext_vector_type(2)));

constexpr int Bc = 16, Tc = 500, Sc = 100, Fc = 35;
constexpr int NPAIR = Bc * Fc;  // 560
constexpr int INIT_E = 56;          // working scale 2^56
constexpr int EXPB = INIT_E + 127;  // renorm target biased exponent

__device__ __forceinline__ float dpp_shr1(float v) {  // lane l <- l-1, fill 0
  return __int_as_float(__builtin_amdgcn_update_dpp(
      0, __float_as_int(v), 0x138, 0xF, 0xF, false));
}
__device__ __forceinline__ float dpp_shl1(float v) {  // lane l <- l+1, fill 0
  return __int_as_float(__builtin_amdgcn_update_dpp(
      0, __float_as_int(v), 0x130, 0xF, 0xF, false));
}
template <int C>
__device__ __forceinline__ int dppmax(int v) {
  int t = __builtin_amdgcn_update_dpp(v, v, C, 0xF, 0xF, false);
  return max(v, t);
}

// 3-class softmax -> float4(q2, q0, q1-q0, 0); log2 domain
__device__ __forceinline__ float4 smf(float xr, float bl2) {
  const float x = xr * LOG2E;
  const float m = fmaxf(fabsf(x), bl2);
  const float u0 = exp2f(-x - m), u1 = exp2f(x - m), u2 = exp2f(bl2 - m);
  const float rz = 1.0f / (u0 + u1 + u2);
  return make_float4(u2 * rz, u0 * rz, (u1 - u0) * rz, 0.0f);
}

// One direction of the scan, packed-fp32 states. BWD=false: alpha,
// t = tstart + i. BWD=true: beta, t = tstart - i. N steps.
// Lane l holds states 4l..4l+3 as u=(e0,e0+2), v=(e0+1,e0+3).
template <bool BWD>
__device__ __forceinline__ void scan_dir(
    const float* __restrict__ lg, float bl2, int Tin, int L, int N,
    int tstart, float bt0f, float bt1f, float skXf, float skYf, int lane,
    float4 (*stg)[64], float& A0, float& A1, float& A2, float& A3,
    int& offOut) {
  f32x2 u = {A0, A2}, v = {A1, A3};
  const f32x2 btv = {bt0f, bt1f};
  const f32x2 skv = {skXf, skYf};
  int off = -INIT_E;
  int mm = 0;

  const int e_hi = 2 * L + 1, twoLm1 = 2 * L - 1;
  const int e0 = 4 * lane;
  const bool in0 = e0 <= e_hi, in1 = e0 + 1 <= e_hi, in2 = e0 + 2 <= e_hi,
             in3 = e0 + 3 <= e_hi;

  auto addr = [&](int i) -> int {  // step index -> clamped time index
    if (BWD) return max(tstart - i, 0);
    return min(tstart + i, Tc - 1);
  };

  auto step = [&](const float4& G) {
    const f32x2 qd = {G.z, G.z}, q0 = {G.y, G.y}, q2 = {G.x, G.x};
    const f32x2 po = __builtin_elementwise_fma(btv, qd, q0);
    if constexpr (!BWD) {
      f32x2 w;
      w.x = dpp_shr1(v.y);  // alpha[4l-1]
      w.y = v.x;            // alpha[4l+1]
      const f32x2 nu = (u + w) * q2;
      const f32x2 nv = __builtin_elementwise_fma(skv, w, u + v) * po;
      u = nu; v = nv;
    } else {
      f32x2 w, z;
      w.x = u.y;            // beta[4l+2]
      w.y = dpp_shl1(u.x);  // beta[4l+4]
      z.x = v.y;            // beta[4l+3]
      z.y = dpp_shl1(v.x);  // beta[4l+5]
      const f32x2 nu = (u + v) * q2;
      const f32x2 nv = __builtin_elementwise_fma(skv, z, v + w) * po;
      u = nu; v = nv;
    }
  };

  auto snap = [&](int istep) {
    if constexpr (!BWD) {
      const int t = tstart + istep;
      const int elo = twoLm1 - 2 * (Tin - 1 - t);
      const int x0 = (in0 && e0 >= elo) ? (__float_as_int(u.x) >> 23) : 0;
      const int x1 = (in1 && e0 + 1 >= elo) ? (__float_as_int(v.x) >> 23) : 0;
      const int x2 = (in2 && e0 + 2 >= elo) ? (__float_as_int(u.y) >> 23) : 0;
      const int x3 = (in3 && e0 + 3 >= elo) ? (__float_as_int(v.y) >> 23) : 0;
      mm = max(max(x0, x1), max(x2, x3));
    } else {
      (void)istep;  // beta: states > 2L are exactly 0, safe unmasked
      const int x0 = __float_as_int(u.x) >> 23, x1 = __float_as_int(v.x) >> 23;
      const int x2 = __float_as_int(u.y) >> 23, x3 = __float_as_int(v.y) >> 23;
      mm = max(max(x0, x1), max(x2, x3));
    }
  };
  auto tree = [&]() {
    mm = dppmax<0x111>(mm); mm = dppmax<0x112>(mm); mm = dppmax<0x114>(mm);
    mm = dppmax<0x118>(mm); mm = dppmax<0x142>(mm); mm = dppmax<0x143>(mm);
  };
  auto apply = [&]() {
    const int mw = __builtin_amdgcn_readlane(mm, 63);
    int k = EXPB - mw;
    k = min(max(k, -126), 126);
    const float sc = __int_as_float((k + 127) << 23);
    const f32x2 sc2 = {sc, sc};
    u *= sc2; v *= sc2;
    off -= k;
  };
  // 8 steps from P, prefetch into Q. doTA: tree early + apply mid-group.
  // doSnap: snapshot at group end. Renorm cadence 32 (see r18 notes).
  auto group = [&](float4 (&P)[8], float4 (&Q)[8], const float4* src,
                   int ilast, bool doTA, bool doSnap) {
#pragma unroll
    for (int i = 0; i < 8; ++i) Q[i] = src[i];
    step(P[0]);
    if (doTA) tree();
    step(P[1]); step(P[2]); step(P[3]);
    if (doTA) apply();
    step(P[4]); step(P[5]); step(P[6]); step(P[7]);
    if (doSnap) snap(ilast);
  };

  // prologue: stage chunk0, preload raw for chunk1, load group0, snapshot
  float xraw = lg[addr(lane) * Fc];
  stg[0][lane] = smf(xraw, bl2);
  xraw = lg[addr(64 + lane) * Fc];
  float4 A[8], B[8];
#pragma unroll
  for (int i = 0; i < 8; ++i) A[i] = stg[0][i];
  snap(-1);

  int buf = 0, ib = 0;
  for (; ib + 64 <= N; ib += 64) {
    if (ib + 64 < N) {
      stg[buf ^ 1][lane] = smf(xraw, bl2);
      xraw = lg[addr(ib + 128 + lane) * Fc];
    }
    const float4* cpA = &stg[buf][0];
    const float4* cpB = &stg[buf ^ 1][0];
#pragma unroll
    for (int d = 0; d < 4; ++d) {
      group(A, B, cpA + 8 * (2 * d + 1), ib + 16 * d + 7,
            (d == 0) || (d == 2), false);
      group(B, A, (d < 3) ? (cpA + 8 * (2 * d + 2)) : cpB, ib + 16 * d + 15,
            false, (d == 1) || (d == 3));
    }
    buf ^= 1;
  }
  {  // tail: n in [0,63], immediate renorm per 8
    const int n = N - ib;
    const float4* cp = &stg[buf][0];
#pragma unroll
    for (int grp = 0; grp < 8; ++grp) {
      if (8 * grp >= n) break;  // wave-uniform
      float4 g[8];
#pragma unroll
      for (int i = 0; i < 8; ++i) g[i] = cp[8 * grp + i];
#pragma unroll
      for (int i = 0; i < 8; ++i) {
        if (8 * grp + i >= n) break;  // wave-uniform
        step(g[i]);
      }
      if (8 * grp + 8 <= n) { snap(ib + 8 * grp + 7); tree(); apply(); }
    }
  }
  A0 = u.x; A1 = v.x; A2 = u.y; A3 = v.y;
  offOut = off;
}

__global__ __launch_bounds__(128) void sctc_scan(
    const float* __restrict__ logits,       // (B,T,F)
    const float* __restrict__ blank_logit,  // (1,)
    const int* __restrict__ targets,        // (B,S,F) 0/1
    const int* __restrict__ in_len,         // (B,)
    const int* __restrict__ tgt_len,        // (B,)
    float* __restrict__ part) {             // (NPAIR,)
  __shared__ float4 stg[2][2][64];  // [wave][dbuf][lane]
  __shared__ float4 xch[64];
  __shared__ int offsh;
  const int tid = threadIdx.x, wid = tid >> 6, lane = tid & 63;
  const int p = blockIdx.x;
  const int b = p / Fc, f = p - b * Fc;
  const int Tin = in_len[b];  // uniform
  const int L = tgt_len[b];   // uniform
  const float bl2 = blank_logit[0] * LOG2E;
  const float* __restrict__ lg = logits + (size_t)b * Tc * Fc + f;
  const float SINI = __int_as_float((INIT_E + 127) << 23);  // 2^INIT_E
  const int e0 = 4 * lane;

  const int tbase = b * Sc * Fc + f;
  const int t0 = targets[tbase + min(2 * lane, Sc - 1) * Fc];
  const int t1 = targets[tbase + min(2 * lane + 1, Sc - 1) * Fc];
  const int tprev = __shfl_up(t1, 1);     // tgt[2l-1]
  const int tnext0 = __shfl_down(t0, 1);  // tgt[2l+2]
  const float bt0f = t0 ? 1.0f : 0.0f, bt1f = t1 ? 1.0f : 0.0f;
  const float sk1f = (lane == 0 || t0 != tprev) ? 1.0f : 0.0f;
  const float sk3f = (t1 != t0) ? 1.0f : 0.0f;
  const float skBf = (tnext0 != t1) ? 1.0f : 0.0f;

  const int tm = Tin >> 1;
  const int NF = tm;            // fwd steps: t = 1..tm
  const int NB = Tin - 2 - tm;  // bwd steps: t = Tin-2..tm+1

  float a0 = 0.0f, a1 = 0.0f, a2 = 0.0f, a3 = 0.0f;
  int off = -INIT_E;

  if (wid == 0) {  // forward alpha
    const float4 c0 = smf(lg[0], bl2);
    if (lane == 0) {
      a0 = c0.x * SINI;
      a1 = fmaf(bt0f, c0.z, c0.y) * SINI;
    }
    scan_dir<false>(lg, bl2, Tin, L, NF, 1, bt0f, bt1f, sk1f, sk3f, lane,
                    stg[0], a0, a1, a2, a3, off);
  } else {  // backward beta
    const float4 cE = smf(lg[(Tin - 1) * Fc], bl2);
    if (e0 == 2 * L) a0 = cE.x * SINI;
    if (e0 + 2 == 2 * L) a2 = cE.x * SINI;
    if (e0 + 1 == 2 * L - 1) a1 = fmaf(bt0f, cE.z, cE.y) * SINI;
    if (e0 + 3 == 2 * L - 1) a3 = fmaf(bt1f, cE.z, cE.y) * SINI;
    scan_dir<true>(lg, bl2, Tin, L, NB, Tin - 2, bt0f, bt1f, sk3f, skBf,
                   lane, stg[1], a0, a1, a2, a3, off);
    // gamma half-step: transition sum of beta_{tm+1} without emission probs
    const float nb0 = dpp_shl1(a0), nb1 = dpp_shl1(a1);
    const float bt0v = a0 + a1;
    const float bt1v = fmaf(a3, sk3f, a1 + a2);
    const float bt2v = a2 + a3;
    const float bt3v = fmaf(nb1, skBf, a3 + nb0);
    xch[lane] = make_float4(bt0v, bt1v, bt2v, bt3v);
    if (lane == 0) offsh = off;
  }
  __syncthreads();
  if (wid == 0) {
    const float4 bb = xch[lane];
    // mask alpha to e <= 2L: out-of-band alphas may be +inf (excluded from
    // renorm max by design); gamma there is exactly 0; inf*0 = NaN guard.
    const int twoL = 2 * L;
    const float z0 = (e0 <= twoL) ? a0 : 0.0f;
    const float z1 = (e0 + 1 <= twoL) ? a1 : 0.0f;
    const float z2 = (e0 + 2 <= twoL) ? a2 : 0.0f;
    const float z3 = (e0 + 3 <= twoL) ? a3 : 0.0f;
    double d = (double)z0 * bb.x + (double)z1 * bb.y + (double)z2 * bb.z +
               (double)z3 * bb.w;
    for (int o = 32; o >= 1; o >>= 1) d += __shfl_down(d, o);
    if (lane == 0) {
      const int offT = off + offsh;
      float val = 0.0f;
      if (d > 0.0) {
        int ex;
        const double mant = frexp(d, &ex);
        const double ll2 = (double)(ex + offT) + log2(mant);
        double ld = -ll2 * LN2d;
        if (ld > 0.5e30) ld = 0.0;  // zero_infinity
        val = (float)(ld / (double)L) * (1.0f / (float)NPAIR);
      }
      part[p] = val;
    }
  }
}

// Slim reduce: 1 wave, 9 batched independent loads (no loop-carried dep),
// fixed-order sum + fixed shuffle tree -> bit-deterministic.
__global__ __launch_bounds__(64) void sctc_reduce(const float* __restrict__ ws,
                                                  float* __restrict__ out) {
  const int lane = threadIdx.x;
  const float v0 = ws[lane];
  const float v1 = ws[lane + 64];
  const float v2 = ws[lane + 128];
  const float v3 = ws[lane + 192];
  const float v4 = ws[lane + 256];
  const float v5 = ws[lane + 320];
  const float v6 = ws[lane + 384];
  const float v7 = ws[lane + 448];
  float v8 = ws[(lane < 48) ? (lane + 512) : lane];
  if (lane >= 48) v8 = 0.0f;
  float s = ((((((((v0 + v1) + v2) + v3) + v4) + v5) + v6) + v7) + v8);
  for (int o = 32; o >= 1; o >>= 1) s += __shfl_xor(s, o);
  if (lane == 0) out[0] = s;
}

extern "C" void kernel_launch(void* const* d_in, const int* in_sizes, int n_in,
                              void* d_out, int out_size, void* d_ws,
                              size_t ws_size, hipStream_t stream) {
  const float* logits = (const float*)d_in[0];
  const float* blank_logit = (const float*)d_in[1];
  const int* targets = (const int*)d_in[2];
  const int* in_len = (const int*)d_in[3];
  const int* tgt_len = (const int*)d_in[4];
  float* part = (float*)d_ws;
  float* out = (float*)d_out;

  sctc_scan<<<NPAIR, 128, 0, stream>>>(logits, blank_logit, targets, in_len,
                                       tgt_len, part);
  sctc_reduce<<<1, 64, 0, stream>>>(part, out);
}